// Round 3
// baseline (486.195 us; speedup 1.0000x reference)
//
#include <hip/hip_runtime.h>
#include <math.h>

#define N_ROWS 131072
#define D_COLS 512
#define TOTAL4 (N_ROWS * D_COLS / 4)   // 16777216 float4 elements

typedef float v4f __attribute__((ext_vector_type(4)));

// Pass 1: per-thread sum / sumsq over a loop-invariant column quad, then
// block-level LDS reduction -> per-block partial sums in d_ws.
// Block = 256 threads; grid stride (= gridDim*256) is a multiple of 128
// float4s, so thread t always owns columns 4*(t%128)..+3.
__global__ __launch_bounds__(256)
void bn_stats_kernel(const v4f* __restrict__ X, float* __restrict__ partial) {
    const int t = threadIdx.x;
    const int g = blockIdx.x * blockDim.x + t;
    const int stride = gridDim.x * blockDim.x;

    v4f s = (v4f)0.0f;
    v4f q = (v4f)0.0f;

    // Unroll 4: four independent 16B loads in flight per iteration.
    #pragma unroll 4
    for (int i = g; i < TOTAL4; i += stride) {
        v4f x = X[i];
        s += x;
        q += x * x;
    }

    __shared__ v4f ls[256];
    __shared__ v4f lq[256];
    ls[t] = s;
    lq[t] = q;
    __syncthreads();

    // threads t and t+128 own the same column quad
    if (t < 128) {
        v4f sv = ls[t] + ls[t + 128];
        v4f qv = lq[t] + lq[t + 128];
        // layout per block: sum[512] then sumsq[512]
        float* dst = partial + (size_t)blockIdx.x * 1024;
        *(v4f*)(dst + 4 * t)       = sv;
        *(v4f*)(dst + 512 + 4 * t) = qv;
    }
}

// Pass 1b: one block per column d. Reduce B per-block partials, emit
// scale[d] = gamma*rsqrt(var), bias[d] = beta - mean*scale.
__global__ __launch_bounds__(256)
void bn_finalize_kernel(const float* __restrict__ partial,
                        const float* __restrict__ gamma,
                        const float* __restrict__ beta,
                        float* __restrict__ scale,
                        float* __restrict__ bias,
                        int B) {
    const int d = blockIdx.x;
    const int t = threadIdx.x;

    float s = 0.f, q = 0.f;
    for (int b = t; b < B; b += blockDim.x) {
        s += partial[(size_t)b * 1024 + d];
        q += partial[(size_t)b * 1024 + 512 + d];
    }

    __shared__ float ls[256];
    __shared__ float lq[256];
    ls[t] = s;
    lq[t] = q;
    __syncthreads();
    for (int off = 128; off > 0; off >>= 1) {
        if (t < off) { ls[t] += ls[t + off]; lq[t] += lq[t + off]; }
        __syncthreads();
    }

    if (t == 0) {
        const float invN = 1.0f / (float)N_ROWS;
        float mean = ls[0] * invN;
        float var  = lq[0] * invN - mean * mean;   // no epsilon, per reference
        float inv  = rsqrtf(var);
        float sc   = gamma[d] * inv;
        scale[d] = sc;
        bias[d]  = beta[d] - mean * sc;
    }
}

// Pass 2: Y = X*scale + bias. Fixed 4-iteration trip count with batched
// loads (4 outstanding 16B loads) then batched nt-stores. Stride is a
// multiple of 128 float4s so scale/bias are loop-invariant per thread.
// nt-stores keep Y out of L3 so X (read by pass 1) stays resident.
#define NORM_GRID 16384
#define NORM_STRIDE (NORM_GRID * 256)   // 4194304 float4s; TOTAL4/stride = 4
__global__ __launch_bounds__(256)
void bn_norm_kernel(const v4f* __restrict__ X,
                    v4f* __restrict__ Y,
                    const float* __restrict__ scale,
                    const float* __restrict__ bias) {
    const int g = blockIdx.x * blockDim.x + threadIdx.x;
    const int c = (g & 127) * 4;

    const v4f sc = *(const v4f*)(scale + c);
    const v4f bi = *(const v4f*)(bias + c);

    v4f x0 = X[g];
    v4f x1 = X[g + NORM_STRIDE];
    v4f x2 = X[g + 2 * NORM_STRIDE];
    v4f x3 = X[g + 3 * NORM_STRIDE];

    __builtin_nontemporal_store(x0 * sc + bi, &Y[g]);
    __builtin_nontemporal_store(x1 * sc + bi, &Y[g + NORM_STRIDE]);
    __builtin_nontemporal_store(x2 * sc + bi, &Y[g + 2 * NORM_STRIDE]);
    __builtin_nontemporal_store(x3 * sc + bi, &Y[g + 3 * NORM_STRIDE]);
}

extern "C" void kernel_launch(void* const* d_in, const int* in_sizes, int n_in,
                              void* d_out, int out_size, void* d_ws, size_t ws_size,
                              hipStream_t stream) {
    const float* X     = (const float*)d_in[0];
    const float* gamma = (const float*)d_in[1];
    const float* beta  = (const float*)d_in[2];
    float* Y  = (float*)d_out;
    float* ws = (float*)d_ws;

    // Fit partials in workspace: B blocks * 1024 floats + 1024 floats scale/bias.
    int B = 1024;
    while (B > 64 && ((size_t)B * 1024 + 1024) * sizeof(float) > ws_size) B >>= 1;

    float* partial = ws;
    float* scale   = ws + (size_t)B * 1024;
    float* bias    = scale + 512;

    bn_stats_kernel<<<B, 256, 0, stream>>>((const v4f*)X, partial);
    bn_finalize_kernel<<<512, 256, 0, stream>>>(partial, gamma, beta, scale, bias, B);
    bn_norm_kernel<<<NORM_GRID, 256, 0, stream>>>((const v4f*)X, (v4f*)Y, scale, bias);
}